// Round 3
// baseline (92.062 us; speedup 1.0000x reference)
//
#include <hip/hip_runtime.h>

#define NN 4
#define CC 21
#define HH 96
#define WW 96
#define RR 5
#define DD 11
#define HW (HH*WW)
#define NPIX (NN*HH*WW)
#define SPLIT 4

__global__ __launch_bounds__(256) void crf_loss_kernel(
    const float* __restrict__ y, const float* __restrict__ rgb,
    float* __restrict__ out)
{
    int idx = blockIdx.x * blockDim.x + threadIdx.x;
    int part = idx / NPIX;            // which quarter of the offset loop
    int pix  = idx - part * NPIX;     // consecutive lanes -> consecutive w (coalesced)
    int n   = pix / HW;
    int rem = pix - n * HW;
    int h   = rem / WW;
    int w   = rem - h * WW;

    const float* yb = y   + n * (CC*HW) + h * WW + w;
    const float* rb = rgb + n * (3*HW)  + h * WW + w;

    float yc[CC];
#pragma unroll
    for (int c = 0; c < CC; ++c) yc[c] = yb[c*HW];
    float r0 = rb[0], r1 = rb[HW], r2 = rb[2*HW];

    // OOB (zero-padded feature) term: exp(-0.5 * ||center_features||^2)
    float ds0   = (float)(w*w + h*h) * (1.f/36.f);
    float drgb0 = (r0*r0 + r1*r1 + r2*r2) * 100.f;
    float koob  = 0.9f*__expf(-0.5f*(ds0 + drgb0)) + 0.1f*__expf(-0.5f*ds0);

    float acc = 0.f;
    for (int t = part; t < DD*DD; t += SPLIT) {
        if (t == (RR*DD + RR)) continue;   // center offset zeroed
        int ty = t / DD;
        int oy = ty - RR;
        int ox = (t - ty*DD) - RR;
        int nh = h + oy, nw = w + ox;
        if (nh >= 0 && nh < HH && nw >= 0 && nw < WW) {
            const float* ynb = yb + oy*WW + ox;
            const float* rnb = rb + oy*WW + ox;
            float d0 = (rnb[0]    - r0) * 10.f;
            float d1 = (rnb[HW]   - r1) * 10.f;
            float d2 = (rnb[2*HW] - r2) * 10.f;
            float ds = (float)(oy*oy + ox*ox) * (1.f/36.f);
            float k  = 0.9f*__expf(-0.5f*(ds + d0*d0 + d1*d1 + d2*d2))
                     + 0.1f*__expf(-0.5f*ds);
            float dot = 0.f;
#pragma unroll
            for (int c = 0; c < CC; ++c) dot = fmaf(yc[c], ynb[c*HW], dot);
            acc += k * (1.f - dot);
        } else {
            acc += koob;
        }
    }

    // wave (64) shuffle reduce
    for (int off = 32; off > 0; off >>= 1)
        acc += __shfl_down(acc, off);
    __shared__ float sdata[4];
    int lane = threadIdx.x & 63;
    int wid  = threadIdx.x >> 6;
    if (lane == 0) sdata[wid] = acc;
    __syncthreads();
    if (threadIdx.x == 0) {
        float s = sdata[0] + sdata[1] + sdata[2] + sdata[3];
        atomicAdd(out, s * (1.f/(float)NPIX));
    }
}

extern "C" void kernel_launch(void* const* d_in, const int* in_sizes, int n_in,
                              void* d_out, int out_size, void* d_ws, size_t ws_size,
                              hipStream_t stream) {
    const float* y   = (const float*)d_in[0];
    const float* rgb = (const float*)d_in[1];
    float* out = (float*)d_out;

    hipMemsetAsync(out, 0, sizeof(float), stream);

    int total  = SPLIT * NPIX;           // 147456 threads
    int blocks = total / 256;            // 576 blocks
    crf_loss_kernel<<<blocks, 256, 0, stream>>>(y, rgb, out);
}

// Round 6
// 83.125 us; speedup vs baseline: 1.1075x; 1.1075x over previous
//
#include <hip/hip_runtime.h>

#define NN 4
#define CC 21
#define HH 96
#define WW 96
#define RR 5
#define DD 11
#define HW (HH*WW)
#define NPIX (NN*HH*WW)
#define SPLIT 6
#define NHALF 60   // offsets with (oy<0) || (oy==0 && ox<0)

__global__ __launch_bounds__(256) void crf_loss_kernel(
    const float* __restrict__ y, const float* __restrict__ rgb,
    float* __restrict__ out)
{
    int idx = blockIdx.x * blockDim.x + threadIdx.x;
    int part = idx / NPIX;            // which slice of the 60 half-offsets
    int pix  = idx - part * NPIX;     // consecutive lanes -> consecutive w (coalesced)
    int n   = pix / HW;
    int rem = pix - n * HW;
    int h   = rem / WW;
    int w   = rem - h * WW;

    const float* yb = y   + n * (CC*HW) + h * WW + w;
    const float* rb = rgb + n * (3*HW)  + h * WW + w;

    float yc[CC];
#pragma unroll
    for (int c = 0; c < CC; ++c) yc[c] = yb[c*HW];
    float r0 = rb[0], r1 = rb[HW], r2 = rb[2*HW];

    float acc = 0.f;   // sum over in-bounds half-offset pairs of k*(1-dot)
    for (int t = part; t < NHALF; t += SPLIT) {
        // map t -> (oy,ox): t<55: oy=-5+t/11, ox=t%11-5 ; t>=55: oy=0, ox=t-60
        int oy, ox;
        if (t < 55) { int ty = t / 11; oy = ty - 5; ox = (t - ty*11) - 5; }
        else        { oy = 0; ox = t - 60; }
        int nh = h + oy, nw = w + ox;
        if (nh >= 0 && nh < HH && nw >= 0 && nw < WW) {
            const float* ynb = yb + oy*WW + ox;
            const float* rnb = rb + oy*WW + ox;
            float d0 = (rnb[0]    - r0) * 10.f;
            float d1 = (rnb[HW]   - r1) * 10.f;
            float d2 = (rnb[2*HW] - r2) * 10.f;
            float ds  = (float)(oy*oy + ox*ox) * (1.f/36.f);
            float e_s = __expf(-0.5f*ds);
            float k   = e_s * (0.9f*__expf(-0.5f*(d0*d0 + d1*d1 + d2*d2)) + 0.1f);
            float dot = 0.f;
#pragma unroll
            for (int c = 0; c < CC; ++c) dot = fmaf(yc[c], ynb[c*HW], dot);
            acc += k * (1.f - dot);
        }
    }
    acc += acc;   // each unordered in-bounds pair appears twice in the full sum

    if (part == 0) {
        // all OOB taps of this pixel: koob * (121 - ry*rx), koob from zero-padded feats
        float ds0   = (float)(w*w + h*h) * (1.f/36.f);
        float drgb0 = (r0*r0 + r1*r1 + r2*r2) * 100.f;
        float koob  = 0.9f*__expf(-0.5f*(ds0 + drgb0)) + 0.1f*__expf(-0.5f*ds0);
        int ry = min(RR, h) + min(RR, HH-1-h) + 1;
        int rx = min(RR, w) + min(RR, WW-1-w) + 1;
        acc += koob * (float)(DD*DD - ry*rx);
    }

    // wave (64) shuffle reduce
    for (int off = 32; off > 0; off >>= 1)
        acc += __shfl_down(acc, off);
    __shared__ float sdata[4];
    int lane = threadIdx.x & 63;
    int wid  = threadIdx.x >> 6;
    if (lane == 0) sdata[wid] = acc;
    __syncthreads();
    if (threadIdx.x == 0) {
        float s = sdata[0] + sdata[1] + sdata[2] + sdata[3];
        atomicAdd(out, s * (1.f/(float)NPIX));
    }
}

extern "C" void kernel_launch(void* const* d_in, const int* in_sizes, int n_in,
                              void* d_out, int out_size, void* d_ws, size_t ws_size,
                              hipStream_t stream) {
    const float* y   = (const float*)d_in[0];
    const float* rgb = (const float*)d_in[1];
    float* out = (float*)d_out;

    hipMemsetAsync(out, 0, sizeof(float), stream);

    int total  = SPLIT * NPIX;           // 221184 threads
    int blocks = total / 256;            // 864 blocks
    crf_loss_kernel<<<blocks, 256, 0, stream>>>(y, rgb, out);
}